// Round 2
// baseline (884.535 us; speedup 1.0000x reference)
//
#include <hip/hip_runtime.h>
#include <hip/hip_bf16.h>
#include <math.h>

#define NEG_INF_F (-3.4028234663852886e38f)

typedef __bf16 bf16_t;
typedef __bf16 bf16x8 __attribute__((ext_vector_type(8)));
typedef __bf16 bf16x4 __attribute__((ext_vector_type(4)));
typedef float f32x4 __attribute__((ext_vector_type(4)));

static constexpr int Bb = 2, Ss = 1024, Hid = 4096, Nh = 32, Dh = 128;
static constexpr int Mr = Bb * Ss;   // 2048 token rows
static constexpr int Bh = Bb * Nh;   // 64 (batch*heads)

__device__ __forceinline__ float wred_max(float v) {
#pragma unroll
  for (int off = 32; off > 0; off >>= 1) v = fmaxf(v, __shfl_xor(v, off));
  return v;
}
__device__ __forceinline__ float wred_sum(float v) {
#pragma unroll
  for (int off = 32; off > 0; off >>= 1) v += __shfl_xor(v, off);
  return v;
}

// ---------------- RoPE cos/sin tables [S][64] ----------------
__global__ void rope_table_kernel(float* __restrict__ ctab, float* __restrict__ stab) {
  int i = blockIdx.x * 256 + threadIdx.x;   // 0 .. S*64-1
  int srow = i >> 6, d = i & 63;
  float invf = (float)pow(10000.0, -((double)(2 * d) / (double)Dh));
  float ang = (float)srow * invf;           // f32 mul like numpy outer()
  ctab[i] = (float)cos((double)ang);
  stab[i] = (float)sin((double)ang);
}

// ------------- per-row symmetric fake-quant: int codes as bf16 + f32 scale -------------
__global__ __launch_bounds__(256) void quant_rows_kernel(
    const float* __restrict__ in, bf16_t* __restrict__ outq,
    float* __restrict__ scale, int ncols, float qmax, float clo, float chi)
{
  const int row = blockIdx.x;
  const float* x = in + (size_t)row * ncols;
  bf16_t* o = outq + (size_t)row * ncols;
  const int tid = threadIdx.x;
  const float4* x4 = (const float4*)x;
  const int n4 = ncols >> 2;
  float m = 0.f;
  for (int i = tid; i < n4; i += 256) {
    float4 v = x4[i];
    m = fmaxf(m, fmaxf(fmaxf(fabsf(v.x), fabsf(v.y)), fmaxf(fabsf(v.z), fabsf(v.w))));
  }
  m = wred_max(m);
  __shared__ float red[4];
  if ((tid & 63) == 0) red[tid >> 6] = m;
  __syncthreads();
  m = fmaxf(fmaxf(red[0], red[1]), fmaxf(red[2], red[3]));
  const float s = fmaxf(m / qmax, 1e-8f);
  if (tid == 0) scale[row] = s;
  bf16x4* o4 = (bf16x4*)o;
  for (int i = tid; i < n4; i += 256) {
    float4 v = x4[i];
    bf16x4 r;
    r[0] = (bf16_t)fminf(fmaxf(rintf(v.x / s), clo), chi);
    r[1] = (bf16_t)fminf(fmaxf(rintf(v.y / s), clo), chi);
    r[2] = (bf16_t)fminf(fmaxf(rintf(v.z / s), clo), chi);
    r[3] = (bf16_t)fminf(fmaxf(rintf(v.w / s), clo), chi);
    o4[i] = r;
  }
}

// ------------- GEMM: C[m,n] = (sum_k A[m,k]*W[n,k]) * sA[m] * sW[n] -------------
// A,W hold exact integer codes in bf16 -> MFMA accumulation is exact integer math.
// mode 0: out[m*N+n]   mode 1: out[((b*Nh+h)*Ss+s)*Dh+d] with b=m>>10,s=m&1023,h=n>>7,d=n&127
#define LDSP 40   // padded LDS row stride (elements)
__global__ __launch_bounds__(256) void gemm_kernel(
    const bf16_t* __restrict__ A, const float* __restrict__ sA,
    const bf16_t* __restrict__ W, const float* __restrict__ sW,
    float* __restrict__ out, int M, int N, int K, int mode)
{
  __shared__ __align__(16) bf16_t As[128 * LDSP];
  __shared__ __align__(16) bf16_t Bs[128 * LDSP];
  const int tid = threadIdx.x, lane = tid & 63, wid = tid >> 6;
  const int bm = blockIdx.x * 128, bn = blockIdx.y * 128;
  const int wm = wid >> 1, wn = wid & 1;
  const int l15 = lane & 15, kof = (lane >> 4) * 8;
  const int srow = tid >> 1, schunk = (tid & 1) * 16;   // 128 rows x 2 chunks of 16 elems

  const bf16_t* gA = A + (size_t)(bm + srow) * K + schunk;
  const bf16_t* gB = W + (size_t)(bn + srow) * K + schunk;
  bf16_t* lA = &As[srow * LDSP + schunk];
  bf16_t* lB = &Bs[srow * LDSP + schunk];

  f32x4 acc[4][4] = {};
  for (int k0 = 0; k0 < K; k0 += 32) {
    // each thread stages 16 bf16 (32 B) of A and of B
    bf16x8 va0 = *(const bf16x8*)(gA + k0);
    bf16x8 va1 = *(const bf16x8*)(gA + k0 + 8);
    bf16x8 vb0 = *(const bf16x8*)(gB + k0);
    bf16x8 vb1 = *(const bf16x8*)(gB + k0 + 8);
    if (k0) __syncthreads();
    *(bf16x8*)lA = va0;
    *(bf16x8*)(lA + 8) = va1;
    *(bf16x8*)lB = vb0;
    *(bf16x8*)(lB + 8) = vb1;
    __syncthreads();
    bf16x8 af[4], bw[4];
#pragma unroll
    for (int f = 0; f < 4; ++f) {
      af[f] = *(const bf16x8*)&As[(wm * 64 + f * 16 + l15) * LDSP + kof];
      bw[f] = *(const bf16x8*)&Bs[(wn * 64 + f * 16 + l15) * LDSP + kof];
    }
#pragma unroll
    for (int fm = 0; fm < 4; ++fm)
#pragma unroll
      for (int fn = 0; fn < 4; ++fn)
        acc[fm][fn] = __builtin_amdgcn_mfma_f32_16x16x32_bf16(af[fm], bw[fn], acc[fm][fn], 0, 0, 0);
  }
#pragma unroll
  for (int fm = 0; fm < 4; ++fm) {
    const int row0 = bm + wm * 64 + fm * 16 + (lane >> 4) * 4;
#pragma unroll
    for (int fn = 0; fn < 4; ++fn) {
      const int col = bn + wn * 64 + fn * 16 + l15;
      const float swv = sW[col];
#pragma unroll
      for (int j = 0; j < 4; ++j) {
        const int row = row0 + j;
        const float val = acc[fm][fn][j] * sA[row] * swv;
        size_t off;
        if (mode == 0) off = (size_t)row * N + col;
        else {
          int b = row >> 10, si = row & 1023, h = col >> 7, d = col & 127;
          off = (((size_t)(b * Nh + h)) * Ss + si) * Dh + d;
        }
        out[off] = val;
      }
    }
  }
}

// ------------- RoPE + per-row(D=128) quant for Q/K; F = ||x|| / (sqrt(sum qi^2) * 128^0.25) -------------
__global__ __launch_bounds__(256) void rope_quant_kernel(
    const float* __restrict__ xin,                 // [Bh*Ss][128]
    const float* __restrict__ ctab, const float* __restrict__ stab,
    bf16_t* __restrict__ xq, float* __restrict__ F)
{
  const int gid = blockIdx.x * 4 + (threadIdx.x >> 6);
  const int lane = threadIdx.x & 63;
  const int srow = gid & (Ss - 1);
  const float* x = xin + (size_t)gid * Dh;
  const float xl = x[lane], xh = x[lane + 64];
  const float c = ctab[srow * 64 + lane], sn = stab[srow * 64 + lane];
  // match numpy's unfused mul/add rounding (no fma contraction)
  const float rl = __fsub_rn(__fmul_rn(xl, c), __fmul_rn(xh, sn));
  const float rh = __fadd_rn(__fmul_rn(xh, c), __fmul_rn(xl, sn));
  const float ma = wred_max(fmaxf(fabsf(rl), fabsf(rh)));
  const float n2 = wred_sum(rl * rl + rh * rh);
  const float s = fmaxf(ma / 127.0f, 1e-8f);
  const float ql = fminf(fmaxf(rintf(rl / s), -128.f), 127.f);
  const float qh = fminf(fmaxf(rintf(rh / s), -128.f), 127.f);
  const float nq2 = wred_sum(ql * ql + qh * qh);
  bf16_t* o = xq + (size_t)gid * Dh;
  o[lane] = (bf16_t)ql;
  o[lane + 64] = (bf16_t)qh;
  if (lane == 0) F[gid] = sqrtf(n2 / nq2) * 0.2973017787506803f;  // 1/128^0.25
}

// ------------- V quant: dequantized bf16 stored transposed [Bh][128][Ss]; a2v factor -------------
__global__ __launch_bounds__(256) void vquant_kernel(
    const float* __restrict__ vin, bf16_t* __restrict__ vdqt, float* __restrict__ a2v)
{
  const int gid = blockIdx.x * 4 + (threadIdx.x >> 6);
  const int lane = threadIdx.x & 63;
  const int bh = gid >> 10, srow = gid & 1023;
  const float* x = vin + (size_t)gid * Dh;
  const float xl = x[lane], xh = x[lane + 64];
  const float ma = wred_max(fmaxf(fabsf(xl), fabsf(xh)));
  const float n2 = wred_sum(xl * xl + xh * xh);
  const float s = fmaxf(ma / 127.0f, 1e-8f);
  const float ql = fminf(fmaxf(rintf(xl / s), -128.f), 127.f);
  const float qh = fminf(fmaxf(rintf(xh / s), -128.f), 127.f);
  const float nq2 = wred_sum(ql * ql + qh * qh);
  const size_t base = (size_t)bh * Dh * Ss;
  vdqt[base + (size_t)lane * Ss + srow] = (bf16_t)(ql * s);
  vdqt[base + (size_t)(lane + 64) * Ss + srow] = (bf16_t)(qh * s);
  if (lane == 0) a2v[gid] = s * sqrtf(nq2) / sqrtf(n2);
}

// ------------- fused attention: scores -> softmax -> P-quant -> PV, per (bh, 16 q-rows) -------------
__global__ __launch_bounds__(256) void attn_kernel(
    const bf16_t* __restrict__ qq, const bf16_t* __restrict__ kq,
    const bf16_t* __restrict__ vdqt,
    const float* __restrict__ Fq, const float* __restrict__ Fk,
    const float* __restrict__ A2v, const float* __restrict__ mask,
    float* __restrict__ oattn)
{
  const int bh = blockIdx.y, b = bh >> 5, h = bh & 31;
  const int q0 = blockIdx.x * 16;
  const int tid = threadIdx.x, lane = tid & 63, wid = tid >> 6;
  const int l15 = lane & 15, kg = lane >> 4, kof = kg * 8;
  __shared__ __align__(16) bf16_t s_pq[16][1024];
  __shared__ float s_rmax[4][16];
  __shared__ float s_rsum[4][16];

  const size_t bhS = (size_t)bh * Ss;
  const bf16_t* qbase = qq + (bhS + q0) * Dh;
  bf16x8 aq[4];
#pragma unroll
  for (int kk = 0; kk < 4; ++kk)
    aq[kk] = *(const bf16x8*)(qbase + l15 * Dh + kk * 32 + kof);
  float fq[4];
#pragma unroll
  for (int j = 0; j < 4; ++j) fq[j] = Fq[bhS + q0 + kg * 4 + j];

  // --- QK^T: this wave owns 256 k-columns; scores live in registers ---
  float sc[16][4];
#pragma unroll
  for (int fc = 0; fc < 16; ++fc) {
    const int kc = wid * 256 + fc * 16;
    const bf16_t* kbase = kq + (bhS + kc) * Dh;
    f32x4 c = {};
#pragma unroll
    for (int kk = 0; kk < 4; ++kk) {
      bf16x8 bk = *(const bf16x8*)(kbase + l15 * Dh + kk * 32 + kof);
      c = __builtin_amdgcn_mfma_f32_16x16x32_bf16(aq[kk], bk, c, 0, 0, 0);
    }
    const int col = kc + l15;
    const float fk = Fk[bhS + col];
    const float* mp = mask + (size_t)b * Ss * Ss + (size_t)(q0 + kg * 4) * Ss + col;
#pragma unroll
    for (int j = 0; j < 4; ++j)
      sc[fc][j] = fmaxf(c[j] * fq[j] * fk + mp[(size_t)j * Ss], NEG_INF_F);
  }
  // --- row max: 16 frags, then 16-lane group, then cross-wave via LDS ---
  float pm[4];
#pragma unroll
  for (int j = 0; j < 4; ++j) {
    float v = sc[0][j];
#pragma unroll
    for (int fc = 1; fc < 16; ++fc) v = fmaxf(v, sc[fc][j]);
#pragma unroll
    for (int off = 1; off < 16; off <<= 1) v = fmaxf(v, __shfl_xor(v, off));
    pm[j] = v;
  }
  if (l15 == 0) {
#pragma unroll
    for (int j = 0; j < 4; ++j) s_rmax[wid][kg * 4 + j] = pm[j];
  }
  __syncthreads();
  float mrow[4], zp[4] = {0.f, 0.f, 0.f, 0.f};
#pragma unroll
  for (int j = 0; j < 4; ++j) {
    const int r = kg * 4 + j;
    mrow[j] = fmaxf(fmaxf(s_rmax[0][r], s_rmax[1][r]), fmaxf(s_rmax[2][r], s_rmax[3][r]));
  }
  // --- exp, Z partial, P-quant into XOR-swizzled LDS (pq = round(127*e), exact) ---
#pragma unroll
  for (int fc = 0; fc < 16; ++fc) {
    const int col = wid * 256 + fc * 16 + l15;
#pragma unroll
    for (int j = 0; j < 4; ++j) {
      const float e = expf(sc[fc][j] - mrow[j]);
      zp[j] += e;
      const float pqv = fminf(rintf(127.0f * e), 127.0f);
      const int r = kg * 4 + j;
      s_pq[r][col ^ ((r & 7) << 3)] = (bf16_t)pqv;
    }
  }
#pragma unroll
  for (int j = 0; j < 4; ++j) {
    float v = zp[j];
#pragma unroll
    for (int off = 1; off < 16; off <<= 1) v += __shfl_xor(v, off);
    zp[j] = v;
  }
  if (l15 == 0) {
#pragma unroll
    for (int j = 0; j < 4; ++j) s_rsum[wid][kg * 4 + j] = zp[j];
  }
  __syncthreads();
  float osc[4];
#pragma unroll
  for (int j = 0; j < 4; ++j) {
    const int r = kg * 4 + j;
    const float Z = ((s_rsum[0][r] + s_rsum[1][r]) + (s_rsum[2][r] + s_rsum[3][r]));
    const float pmax = 1.0f / Z;                  // softmax row max
    const float sp = fmaxf(pmax / 127.0f, 1e-8f); // p scale
    osc[j] = sp / A2v[bhS + q0 + r];
  }
  // --- PV: this wave owns 32 of 128 d-columns ---
  f32x4 oacc[2] = {};
  const int d0 = wid * 32;
  const bf16_t* vb0 = vdqt + ((size_t)bh * Dh + d0 + l15) * Ss;
  const bf16_t* vb1 = vb0 + (size_t)16 * Ss;
#pragma unroll 4
  for (int kk = 0; kk < 32; ++kk) {
    const int kidx = kk * 32 + kof;
    bf16x8 ap = *(const bf16x8*)&s_pq[l15][kidx ^ ((l15 & 7) << 3)];
    bf16x8 b0 = *(const bf16x8*)(vb0 + kidx);
    bf16x8 b1 = *(const bf16x8*)(vb1 + kidx);
    oacc[0] = __builtin_amdgcn_mfma_f32_16x16x32_bf16(ap, b0, oacc[0], 0, 0, 0);
    oacc[1] = __builtin_amdgcn_mfma_f32_16x16x32_bf16(ap, b1, oacc[1], 0, 0, 0);
  }
#pragma unroll
  for (int f = 0; f < 2; ++f) {
    const int col = d0 + f * 16 + l15;
#pragma unroll
    for (int j = 0; j < 4; ++j) {
      const int r = kg * 4 + j;
      oattn[((size_t)b * Ss + q0 + r) * Hid + h * Dh + col] = oacc[f][j] * osc[j];
    }
  }
}

extern "C" void kernel_launch(void* const* d_in, const int* in_sizes, int n_in,
                              void* d_out, int out_size, void* d_ws, size_t ws_size,
                              hipStream_t stream)
{
  const float* hidden = (const float*)d_in[0];
  const float* wq = (const float*)d_in[1];
  const float* wk = (const float*)d_in[2];
  const float* wv = (const float*)d_in[3];
  const float* wo = (const float*)d_in[4];
  const float* mask = (const float*)d_in[5];
  float* out = (float*)d_out;

  // ---- workspace layout with aggressive reuse (~130 MiB total) ----
  char* p = (char*)d_ws;
  auto alloc = [&](size_t bytes) -> char* {
    char* r = p; p += (bytes + 255) & ~(size_t)255; return r;
  };
  bf16_t* xq   = (bf16_t*)alloc((size_t)Mr * Hid * sizeof(bf16_t));    // 16 MiB (act codes; later reused for oq)
  bf16_t* wbuf = (bf16_t*)alloc((size_t)Hid * Hid * sizeof(bf16_t));   // 32 MiB (shared weight codes)
  float*  projf= (float*) alloc((size_t)Bh * Ss * Dh * sizeof(float)); // 32 MiB (shared proj out; later oat)
  bf16_t* qqb  = (bf16_t*)alloc((size_t)Bh * Ss * Dh * sizeof(bf16_t));// 16 MiB
  bf16_t* kqb  = (bf16_t*)alloc((size_t)Bh * Ss * Dh * sizeof(bf16_t));// 16 MiB
  bf16_t* vdqt = (bf16_t*)alloc((size_t)Bh * Dh * Ss * sizeof(bf16_t));// 16 MiB
  float* sxa = (float*)alloc((size_t)Mr * sizeof(float));
  float* sw  = (float*)alloc((size_t)Hid * sizeof(float));
  float* Fq  = (float*)alloc((size_t)Bh * Ss * sizeof(float));
  float* Fk  = (float*)alloc((size_t)Bh * Ss * sizeof(float));
  float* A2v = (float*)alloc((size_t)Bh * Ss * sizeof(float));
  float* soa = (float*)alloc((size_t)Mr * sizeof(float));
  float* ctab = (float*)alloc((size_t)Ss * 64 * sizeof(float));
  float* stab = (float*)alloc((size_t)Ss * 64 * sizeof(float));
  float*  oat = projf;           // projf dead after vquant
  bf16_t* oq  = xq;              // xq dead after the three projections

  rope_table_kernel<<<Ss * 64 / 256, 256, 0, stream>>>(ctab, stab);
  quant_rows_kernel<<<Mr, 256, 0, stream>>>(hidden, xq, sxa, Hid, 127.f, -128.f, 127.f);

  dim3 gg(Mr / 128, Hid / 128);
  // Q
  quant_rows_kernel<<<Hid, 256, 0, stream>>>(wq, wbuf, sw, Hid, 7.f, -8.f, 7.f);
  gemm_kernel<<<gg, 256, 0, stream>>>(xq, sxa, wbuf, sw, projf, Mr, Hid, Hid, 1);
  rope_quant_kernel<<<Bh * Ss / 4, 256, 0, stream>>>(projf, ctab, stab, qqb, Fq);
  // K
  quant_rows_kernel<<<Hid, 256, 0, stream>>>(wk, wbuf, sw, Hid, 7.f, -8.f, 7.f);
  gemm_kernel<<<gg, 256, 0, stream>>>(xq, sxa, wbuf, sw, projf, Mr, Hid, Hid, 1);
  rope_quant_kernel<<<Bh * Ss / 4, 256, 0, stream>>>(projf, ctab, stab, kqb, Fk);
  // V
  quant_rows_kernel<<<Hid, 256, 0, stream>>>(wv, wbuf, sw, Hid, 7.f, -8.f, 7.f);
  gemm_kernel<<<gg, 256, 0, stream>>>(xq, sxa, wbuf, sw, projf, Mr, Hid, Hid, 1);
  vquant_kernel<<<Bh * Ss / 4, 256, 0, stream>>>(projf, vdqt, A2v);

  dim3 ga(Ss / 16, Bh);
  attn_kernel<<<ga, 256, 0, stream>>>(qqb, kqb, vdqt, Fq, Fk, A2v, mask, oat);

  quant_rows_kernel<<<Mr, 256, 0, stream>>>(oat, oq, soa, Hid, 127.f, -128.f, 127.f);
  quant_rows_kernel<<<Hid, 256, 0, stream>>>(wo, wbuf, sw, Hid, 7.f, -8.f, 7.f);
  gemm_kernel<<<gg, 256, 0, stream>>>(oq, soa, wbuf, sw, out, Mr, Hid, Hid, 0);
}

// Round 3
// 723.974 us; speedup vs baseline: 1.2218x; 1.2218x over previous
//
#include <hip/hip_runtime.h>
#include <hip/hip_bf16.h>
#include <math.h>

#define NEG_INF_F (-3.4028234663852886e38f)

typedef __bf16 bf16_t;
typedef __bf16 bf16x8 __attribute__((ext_vector_type(8)));
typedef __bf16 bf16x4 __attribute__((ext_vector_type(4)));
typedef float f32x4 __attribute__((ext_vector_type(4)));

static constexpr int Bb = 2, Ss = 1024, Hid = 4096, Nh = 32, Dh = 128;
static constexpr int Mr = Bb * Ss;   // 2048 token rows
static constexpr int Bh = Bb * Nh;   // 64 (batch*heads)

__device__ __forceinline__ void gload_lds16(const bf16_t* g, bf16_t* l) {
  __builtin_amdgcn_global_load_lds((const __attribute__((address_space(1))) void*)g,
                                   (__attribute__((address_space(3))) void*)l, 16, 0, 0);
}

__device__ __forceinline__ float wred_max(float v) {
#pragma unroll
  for (int off = 32; off > 0; off >>= 1) v = fmaxf(v, __shfl_xor(v, off));
  return v;
}

// ---------------- RoPE cos/sin tables [S][64] ----------------
__global__ void rope_table_kernel(float* __restrict__ ctab, float* __restrict__ stab) {
  int i = blockIdx.x * 256 + threadIdx.x;   // 0 .. S*64-1
  int srow = i >> 6, d = i & 63;
  float invf = (float)pow(10000.0, -((double)(2 * d) / (double)Dh));
  float ang = (float)srow * invf;           // f32 mul like numpy outer()
  ctab[i] = (float)cos((double)ang);
  stab[i] = (float)sin((double)ang);
}

// ------------- per-row symmetric fake-quant: int codes as bf16 + f32 scale -------------
__global__ __launch_bounds__(256) void quant_rows_kernel(
    const float* __restrict__ in, bf16_t* __restrict__ outq,
    float* __restrict__ scale, int ncols, float qmax, float clo, float chi)
{
  const int row = blockIdx.x;
  const float* x = in + (size_t)row * ncols;
  bf16_t* o = outq + (size_t)row * ncols;
  const int tid = threadIdx.x;
  const float4* x4 = (const float4*)x;
  const int n4 = ncols >> 2;
  float m = 0.f;
  for (int i = tid; i < n4; i += 256) {
    float4 v = x4[i];
    m = fmaxf(m, fmaxf(fmaxf(fabsf(v.x), fabsf(v.y)), fmaxf(fabsf(v.z), fabsf(v.w))));
  }
  m = wred_max(m);
  __shared__ float red[4];
  if ((tid & 63) == 0) red[tid >> 6] = m;
  __syncthreads();
  m = fmaxf(fmaxf(red[0], red[1]), fmaxf(red[2], red[3]));
  const float s = fmaxf(m / qmax, 1e-8f);
  if (tid == 0) scale[row] = s;
  bf16x4* o4 = (bf16x4*)o;
  for (int i = tid; i < n4; i += 256) {
    float4 v = x4[i];
    bf16x4 r;
    r[0] = (bf16_t)fminf(fmaxf(rintf(v.x / s), clo), chi);
    r[1] = (bf16_t)fminf(fmaxf(rintf(v.y / s), clo), chi);
    r[2] = (bf16_t)fminf(fmaxf(rintf(v.z / s), clo), chi);
    r[3] = (bf16_t)fminf(fmaxf(rintf(v.w / s), clo), chi);
    o4[i] = r;
  }
}

// ------------- GEMM: C[m,n] = (sum_k A[m,k]*W[n,k]) * sA[m] * sW[n] -------------
// m97 structure: global_load_lds width-16 staging into linear [128][32] LDS tiles.
// mode 0: out[m*N+n]   mode 1: out[((b*Nh+h)*Ss+s)*Dh+d]
__global__ __launch_bounds__(256) void gemm_kernel(
    const bf16_t* __restrict__ A, const float* __restrict__ sA,
    const bf16_t* __restrict__ W, const float* __restrict__ sW,
    float* __restrict__ out, int M, int N, int K, int mode)
{
  __shared__ __align__(16) bf16_t As[128 * 32];
  __shared__ __align__(16) bf16_t Bs[128 * 32];
  const int tid = threadIdx.x, lane = tid & 63, wid = tid >> 6;
  const int bm = blockIdx.x * 128, bn = blockIdx.y * 128;
  const int wm = wid >> 1, wn = wid & 1;
  const int l15 = lane & 15, kof = (lane >> 4) * 8;

  // staging: issue r in {0,1}: LDS elem = r*2048 + wid*512 + lane*8
  //   -> row = r*64 + wid*16 + (lane>>2), kin = (lane&3)*8
  const int srow = wid * 16 + (lane >> 2);
  const int skin = (lane & 3) * 8;
  const bf16_t* gA = A + (size_t)(bm + srow) * K + skin;
  const bf16_t* gB = W + (size_t)(bn + srow) * K + skin;
  const size_t half = (size_t)64 * K;
  bf16_t* lA = As + wid * 512;   // wave-uniform base; HW adds lane*16B
  bf16_t* lB = Bs + wid * 512;

  f32x4 acc[4][4] = {};
  for (int k0 = 0; k0 < K; k0 += 32) {
    if (k0) __syncthreads();
    gload_lds16(gA + k0, lA);
    gload_lds16(gA + k0 + half, lA + 2048);
    gload_lds16(gB + k0, lB);
    gload_lds16(gB + k0 + half, lB + 2048);
    __syncthreads();
    bf16x8 af[4], bw[4];
#pragma unroll
    for (int f = 0; f < 4; ++f) {
      af[f] = *(const bf16x8*)&As[(wm * 64 + f * 16 + l15) * 32 + kof];
      bw[f] = *(const bf16x8*)&Bs[(wn * 64 + f * 16 + l15) * 32 + kof];
    }
#pragma unroll
    for (int fm = 0; fm < 4; ++fm)
#pragma unroll
      for (int fn = 0; fn < 4; ++fn)
        acc[fm][fn] = __builtin_amdgcn_mfma_f32_16x16x32_bf16(af[fm], bw[fn], acc[fm][fn], 0, 0, 0);
  }
#pragma unroll
  for (int fm = 0; fm < 4; ++fm) {
    const int row0 = bm + wm * 64 + fm * 16 + (lane >> 4) * 4;
#pragma unroll
    for (int fn = 0; fn < 4; ++fn) {
      const int col = bn + wn * 64 + fn * 16 + l15;
      const float swv = sW[col];
#pragma unroll
      for (int j = 0; j < 4; ++j) {
        const int row = row0 + j;
        const float val = acc[fm][fn][j] * sA[row] * swv;
        size_t off;
        if (mode == 0) off = (size_t)row * N + col;
        else {
          int b = row >> 10, si = row & 1023, h = col >> 7, d = col & 127;
          off = (((size_t)(b * Nh + h)) * Ss + si) * Dh + d;
        }
        out[off] = val;
      }
    }
  }
}

// ------------- RoPE + per-row(D=128) quant for Q/K; F = ||x|| / (sqrt(sum qi^2) * 128^0.25) -------------
__global__ __launch_bounds__(256) void rope_quant_kernel(
    const float* __restrict__ xin,                 // [Bh*Ss][128]
    const float* __restrict__ ctab, const float* __restrict__ stab,
    bf16_t* __restrict__ xq, float* __restrict__ F)
{
  const int gid = blockIdx.x * 4 + (threadIdx.x >> 6);
  const int lane = threadIdx.x & 63;
  const int srow = gid & (Ss - 1);
  const float* x = xin + (size_t)gid * Dh;
  const float xl = x[lane], xh = x[lane + 64];
  const float c = ctab[srow * 64 + lane], sn = stab[srow * 64 + lane];
  // match numpy's unfused mul/add rounding (no fma contraction)
  const float rl = __fsub_rn(__fmul_rn(xl, c), __fmul_rn(xh, sn));
  const float rh = __fadd_rn(__fmul_rn(xh, c), __fmul_rn(xl, sn));
  float ma = fmaxf(fabsf(rl), fabsf(rh));
  float n2 = rl * rl + rh * rh;
#pragma unroll
  for (int off = 32; off > 0; off >>= 1) {
    ma = fmaxf(ma, __shfl_xor(ma, off));
    n2 += __shfl_xor(n2, off);
  }
  const float s = fmaxf(ma / 127.0f, 1e-8f);
  const float ql = fminf(fmaxf(rintf(rl / s), -128.f), 127.f);
  const float qh = fminf(fmaxf(rintf(rh / s), -128.f), 127.f);
  float nq2 = ql * ql + qh * qh;
#pragma unroll
  for (int off = 32; off > 0; off >>= 1) nq2 += __shfl_xor(nq2, off);
  bf16_t* o = xq + (size_t)gid * Dh;
  o[lane] = (bf16_t)ql;
  o[lane + 64] = (bf16_t)qh;
  if (lane == 0) F[gid] = sqrtf(n2 / nq2) * 0.2973017787506803f;  // 1/128^0.25
}

// ------------- V quant: dequant bf16 stored transposed [Bh][128][Ss] via LDS; a2v factor -------------
// block: 256 threads handle 64 tokens of one bh; 16-lane groups own one token each (4 iters).
__global__ __launch_bounds__(256) void vquant_kernel(
    const float* __restrict__ vin, bf16_t* __restrict__ vdqt, float* __restrict__ a2v)
{
  __shared__ bf16_t s_v[128 * 66];
  const int tid = threadIdx.x, lane = tid & 63;
  const int l15 = lane & 15;
  const int qw = (tid >> 6) * 4 + (lane >> 4);   // quarter-wave id 0..15
  const int bh = blockIdx.x >> 4;
  const int t0 = (blockIdx.x & 15) * 64;
  for (int it = 0; it < 4; ++it) {
    const int tt = qw * 4 + it;                   // 0..63
    const size_t gid = (size_t)bh * Ss + t0 + tt;
    const float4 va = *(const float4*)(vin + gid * Dh + l15 * 8);
    const float4 vb = *(const float4*)(vin + gid * Dh + l15 * 8 + 4);
    float m = fmaxf(fmaxf(fmaxf(fabsf(va.x), fabsf(va.y)), fmaxf(fabsf(va.z), fabsf(va.w))),
                    fmaxf(fmaxf(fabsf(vb.x), fabsf(vb.y)), fmaxf(fabsf(vb.z), fabsf(vb.w))));
    float n2 = va.x * va.x + va.y * va.y + va.z * va.z + va.w * va.w +
               vb.x * vb.x + vb.y * vb.y + vb.z * vb.z + vb.w * vb.w;
#pragma unroll
    for (int off = 1; off < 16; off <<= 1) {
      m = fmaxf(m, __shfl_xor(m, off));
      n2 += __shfl_xor(n2, off);
    }
    const float s = fmaxf(m / 127.0f, 1e-8f);
    float q[8] = {va.x, va.y, va.z, va.w, vb.x, vb.y, vb.z, vb.w};
    float nq2 = 0.f;
#pragma unroll
    for (int e = 0; e < 8; ++e) {
      q[e] = fminf(fmaxf(rintf(q[e] / s), -128.f), 127.f);
      nq2 += q[e] * q[e];
      s_v[(l15 * 8 + e) * 66 + tt] = (bf16_t)(q[e] * s);
    }
#pragma unroll
    for (int off = 1; off < 16; off <<= 1) nq2 += __shfl_xor(nq2, off);
    if (l15 == 0) a2v[gid] = s * sqrtf(nq2) / sqrtf(n2);
  }
  __syncthreads();
  // coalesced write-out: thread -> (row, half): 32 bf16 = 64 B
  const int r = tid >> 1, hc = (tid & 1) * 32;
  const bf16_t* src = &s_v[r * 66 + hc];
  bf16_t* dst = vdqt + ((size_t)bh * Dh + r) * Ss + t0 + hc;
#pragma unroll
  for (int k = 0; k < 4; ++k) {
    bf16x8 t;
#pragma unroll
    for (int e = 0; e < 8; ++e) t[e] = src[k * 8 + e];
    *(bf16x8*)(dst + k * 8) = t;
  }
}

// ------------- fused attention: causal (no mask reads), scores -> softmax -> P-quant -> PV -------------
__global__ __launch_bounds__(256) void attn_kernel(
    const bf16_t* __restrict__ qq, const bf16_t* __restrict__ kq,
    const bf16_t* __restrict__ vdqt,
    const float* __restrict__ Fq, const float* __restrict__ Fk,
    const float* __restrict__ A2v, float* __restrict__ oattn)
{
  const int bh = blockIdx.y, b = bh >> 5, h = bh & 31;
  const int q0 = blockIdx.x * 16;
  const int nfc2 = ((int)blockIdx.x + 2) & ~1;   // 16-col chunks, rounded to even (32-col PV steps)
  const int tid = threadIdx.x, lane = tid & 63, wid = tid >> 6;
  const int l15 = lane & 15, kg = lane >> 4, kof = kg * 8;
  __shared__ __align__(16) bf16_t s_pq[16][1024];
  __shared__ float s_rmax[4][16];
  __shared__ float s_rsum[4][16];

  const size_t bhS = (size_t)bh * Ss;
  const bf16_t* qbase = qq + (bhS + q0) * Dh;
  bf16x8 aq[4];
#pragma unroll
  for (int kk = 0; kk < 4; ++kk)
    aq[kk] = *(const bf16x8*)(qbase + l15 * Dh + kk * 32 + kof);
  float fq[4];
#pragma unroll
  for (int j = 0; j < 4; ++j) fq[j] = Fq[bhS + q0 + kg * 4 + j];

  // --- QK^T over causal range; wave wid handles chunks wid, wid+4, ... < nfc2 ---
  float sc[16][4];
  float pm[4] = {NEG_INF_F, NEG_INF_F, NEG_INF_F, NEG_INF_F};
#pragma unroll
  for (int i = 0; i < 16; ++i) {
    const int fc = wid + i * 4;
    if (fc >= nfc2) break;
    const int kc = fc * 16;
    const bf16_t* kbase = kq + (bhS + kc) * Dh;
    f32x4 c = {};
#pragma unroll
    for (int kk = 0; kk < 4; ++kk) {
      bf16x8 bk = *(const bf16x8*)(kbase + l15 * Dh + kk * 32 + kof);
      c = __builtin_amdgcn_mfma_f32_16x16x32_bf16(aq[kk], bk, c, 0, 0, 0);
    }
    const int col = kc + l15;
    const float fk = Fk[bhS + col];
#pragma unroll
    for (int j = 0; j < 4; ++j) {
      const float v = c[j] * fq[j] * fk;
      sc[i][j] = (col <= q0 + kg * 4 + j) ? v : NEG_INF_F;   // exact causal mask
      pm[j] = fmaxf(pm[j], sc[i][j]);
    }
  }
  // --- row max: 16-lane group, then cross-wave via LDS ---
#pragma unroll
  for (int j = 0; j < 4; ++j) {
#pragma unroll
    for (int off = 1; off < 16; off <<= 1) pm[j] = fmaxf(pm[j], __shfl_xor(pm[j], off));
  }
  if (l15 == 0) {
#pragma unroll
    for (int j = 0; j < 4; ++j) s_rmax[wid][kg * 4 + j] = pm[j];
  }
  __syncthreads();
  float mrow[4], zp[4] = {0.f, 0.f, 0.f, 0.f};
#pragma unroll
  for (int j = 0; j < 4; ++j) {
    const int r = kg * 4 + j;
    mrow[j] = fmaxf(fmaxf(s_rmax[0][r], s_rmax[1][r]), fmaxf(s_rmax[2][r], s_rmax[3][r]));
  }
  // --- exp, Z partial, P-quant into XOR-swizzled LDS (pq = round(127*e), exact) ---
#pragma unroll
  for (int i = 0; i < 16; ++i) {
    const int fc = wid + i * 4;
    if (fc >= nfc2) break;
    const int col = fc * 16 + l15;
#pragma unroll
    for (int j = 0; j < 4; ++j) {
      const float e = __expf(sc[i][j] - mrow[j]);
      zp[j] += e;
      const int r = kg * 4 + j;
      s_pq[r][col ^ ((r & 7) << 3)] = (bf16_t)fminf(rintf(127.0f * e), 127.0f);
    }
  }
#pragma unroll
  for (int j = 0; j < 4; ++j) {
#pragma unroll
    for (int off = 1; off < 16; off <<= 1) zp[j] += __shfl_xor(zp[j], off);
  }
  if (l15 == 0) {
#pragma unroll
    for (int j = 0; j < 4; ++j) s_rsum[wid][kg * 4 + j] = zp[j];
  }
  __syncthreads();
  float osc[4];
#pragma unroll
  for (int j = 0; j < 4; ++j) {
    const int r = kg * 4 + j;
    const float Z = ((s_rsum[0][r] + s_rsum[1][r]) + (s_rsum[2][r] + s_rsum[3][r]));
    const float pmax = 1.0f / Z;                  // softmax row max
    const float sp = fmaxf(pmax / 127.0f, 1e-8f); // p scale
    osc[j] = sp / A2v[bhS + q0 + r];
  }
  // --- PV over causal range: this wave owns 32 of 128 d-columns ---
  const int nkk = nfc2 >> 1;
  f32x4 oacc[2] = {};
  const int d0 = wid * 32;
  const bf16_t* vb0 = vdqt + ((size_t)bh * Dh + d0 + l15) * Ss;
  const bf16_t* vb1 = vb0 + (size_t)16 * Ss;
  for (int kk = 0; kk < nkk; ++kk) {
    const int kidx = kk * 32 + kof;
    bf16x8 ap = *(const bf16x8*)&s_pq[l15][kidx ^ ((l15 & 7) << 3)];
    bf16x8 b0 = *(const bf16x8*)(vb0 + kidx);
    bf16x8 b1 = *(const bf16x8*)(vb1 + kidx);
    oacc[0] = __builtin_amdgcn_mfma_f32_16x16x32_bf16(ap, b0, oacc[0], 0, 0, 0);
    oacc[1] = __builtin_amdgcn_mfma_f32_16x16x32_bf16(ap, b1, oacc[1], 0, 0, 0);
  }
#pragma unroll
  for (int f = 0; f < 2; ++f) {
    const int col = d0 + f * 16 + l15;
#pragma unroll
    for (int j = 0; j < 4; ++j) {
      const int r = kg * 4 + j;
      oattn[((size_t)b * Ss + q0 + r) * Hid + h * Dh + col] = oacc[f][j] * osc[j];
    }
  }
}

extern "C" void kernel_launch(void* const* d_in, const int* in_sizes, int n_in,
                              void* d_out, int out_size, void* d_ws, size_t ws_size,
                              hipStream_t stream)
{
  const float* hidden = (const float*)d_in[0];
  const float* wq = (const float*)d_in[1];
  const float* wk = (const float*)d_in[2];
  const float* wv = (const float*)d_in[3];
  const float* wo = (const float*)d_in[4];
  float* out = (float*)d_out;

  // ---- workspace layout with aggressive reuse (~130 MiB total) ----
  char* p = (char*)d_ws;
  auto alloc = [&](size_t bytes) -> char* {
    char* r = p; p += (bytes + 255) & ~(size_t)255; return r;
  };
  bf16_t* xq   = (bf16_t*)alloc((size_t)Mr * Hid * sizeof(bf16_t));    // act codes; later reused for oq
  bf16_t* wbuf = (bf16_t*)alloc((size_t)Hid * Hid * sizeof(bf16_t));   // shared weight codes
  float*  projf= (float*) alloc((size_t)Bh * Ss * Dh * sizeof(float)); // shared proj out; later oat
  bf16_t* qqb  = (bf16_t*)alloc((size_t)Bh * Ss * Dh * sizeof(bf16_t));
  bf16_t* kqb  = (bf16_t*)alloc((size_t)Bh * Ss * Dh * sizeof(bf16_t));
  bf16_t* vdqt = (bf16_t*)alloc((size_t)Bh * Dh * Ss * sizeof(bf16_t));
  float* sxa = (float*)alloc((size_t)Mr * sizeof(float));
  float* sw  = (float*)alloc((size_t)Hid * sizeof(float));
  float* Fq  = (float*)alloc((size_t)Bh * Ss * sizeof(float));
  float* Fk  = (float*)alloc((size_t)Bh * Ss * sizeof(float));
  float* A2v = (float*)alloc((size_t)Bh * Ss * sizeof(float));
  float* soa = (float*)alloc((size_t)Mr * sizeof(float));
  float* ctab = (float*)alloc((size_t)Ss * 64 * sizeof(float));
  float* stab = (float*)alloc((size_t)Ss * 64 * sizeof(float));
  float*  oat = projf;           // projf dead after vquant
  bf16_t* oq  = xq;              // xq dead after the three projections

  rope_table_kernel<<<Ss * 64 / 256, 256, 0, stream>>>(ctab, stab);
  quant_rows_kernel<<<Mr, 256, 0, stream>>>(hidden, xq, sxa, Hid, 127.f, -128.f, 127.f);

  dim3 gg(Mr / 128, Hid / 128);
  // Q
  quant_rows_kernel<<<Hid, 256, 0, stream>>>(wq, wbuf, sw, Hid, 7.f, -8.f, 7.f);
  gemm_kernel<<<gg, 256, 0, stream>>>(xq, sxa, wbuf, sw, projf, Mr, Hid, Hid, 1);
  rope_quant_kernel<<<Bh * Ss / 4, 256, 0, stream>>>(projf, ctab, stab, qqb, Fq);
  // K
  quant_rows_kernel<<<Hid, 256, 0, stream>>>(wk, wbuf, sw, Hid, 7.f, -8.f, 7.f);
  gemm_kernel<<<gg, 256, 0, stream>>>(xq, sxa, wbuf, sw, projf, Mr, Hid, Hid, 1);
  rope_quant_kernel<<<Bh * Ss / 4, 256, 0, stream>>>(projf, ctab, stab, kqb, Fk);
  // V
  quant_rows_kernel<<<Hid, 256, 0, stream>>>(wv, wbuf, sw, Hid, 7.f, -8.f, 7.f);
  gemm_kernel<<<gg, 256, 0, stream>>>(xq, sxa, wbuf, sw, projf, Mr, Hid, Hid, 1);
  vquant_kernel<<<Bh * 16, 256, 0, stream>>>(projf, vdqt, A2v);

  dim3 ga(Ss / 16, Bh);
  attn_kernel<<<ga, 256, 0, stream>>>(qqb, kqb, vdqt, Fq, Fk, A2v, oat);

  quant_rows_kernel<<<Mr, 256, 0, stream>>>(oat, oq, soa, Hid, 127.f, -128.f, 127.f);
  quant_rows_kernel<<<Hid, 256, 0, stream>>>(wo, wbuf, sw, Hid, 7.f, -8.f, 7.f);
  gemm_kernel<<<gg, 256, 0, stream>>>(oq, soa, wbuf, sw, out, Mr, Hid, Hid, 0);
}

// Round 4
// 544.016 us; speedup vs baseline: 1.6259x; 1.3308x over previous
//
#include <hip/hip_runtime.h>
#include <hip/hip_bf16.h>
#include <math.h>
#include <stdint.h>

#define NEG_INF_F (-3.4028234663852886e38f)

typedef __bf16 bf16_t;
typedef __bf16 bf16x8 __attribute__((ext_vector_type(8)));
typedef float f32x4 __attribute__((ext_vector_type(4)));
typedef int i32x4 __attribute__((ext_vector_type(4)));
typedef int8_t c8x4 __attribute__((ext_vector_type(4)));

static constexpr int Bb = 2, Ss = 1024, Hid = 4096, Nh = 32, Dh = 128;
static constexpr int Mr = Bb * Ss;   // 2048 token rows
static constexpr int Bh = Bb * Nh;   // 64 (batch*heads)

__device__ __forceinline__ void gload_lds16(const void* g, void* l) {
  __builtin_amdgcn_global_load_lds((const __attribute__((address_space(1))) void*)g,
                                   (__attribute__((address_space(3))) void*)l, 16, 0, 0);
}

__device__ __forceinline__ float wred_max(float v) {
#pragma unroll
  for (int off = 32; off > 0; off >>= 1) v = fmaxf(v, __shfl_xor(v, off));
  return v;
}

// ---------------- RoPE cos/sin tables [S][64] ----------------
__global__ void rope_table_kernel(float* __restrict__ ctab, float* __restrict__ stab) {
  int i = blockIdx.x * 256 + threadIdx.x;   // 0 .. S*64-1
  int srow = i >> 6, d = i & 63;
  float invf = (float)pow(10000.0, -((double)(2 * d) / (double)Dh));
  float ang = (float)srow * invf;           // f32 mul like numpy outer()
  ctab[i] = (float)cos((double)ang);
  stab[i] = (float)sin((double)ang);
}

// ------------- per-row symmetric fake-quant: int8 codes + f32 scale -------------
__global__ __launch_bounds__(256) void quant_rows_kernel(
    const float* __restrict__ in, int8_t* __restrict__ outq,
    float* __restrict__ scale, int ncols, float qmax, float clo, float chi)
{
  const int row = blockIdx.x;
  const float* x = in + (size_t)row * ncols;
  int8_t* o = outq + (size_t)row * ncols;
  const int tid = threadIdx.x;
  const float4* x4 = (const float4*)x;
  const int n4 = ncols >> 2;
  float m = 0.f;
  for (int i = tid; i < n4; i += 256) {
    float4 v = x4[i];
    m = fmaxf(m, fmaxf(fmaxf(fabsf(v.x), fabsf(v.y)), fmaxf(fabsf(v.z), fabsf(v.w))));
  }
  m = wred_max(m);
  __shared__ float red[4];
  if ((tid & 63) == 0) red[tid >> 6] = m;
  __syncthreads();
  m = fmaxf(fmaxf(red[0], red[1]), fmaxf(red[2], red[3]));
  const float s = fmaxf(m / qmax, 1e-8f);
  if (tid == 0) scale[row] = s;
  c8x4* o4 = (c8x4*)o;
  for (int i = tid; i < n4; i += 256) {
    float4 v = x4[i];
    c8x4 r;
    r[0] = (int8_t)(int)fminf(fmaxf(rintf(v.x / s), clo), chi);
    r[1] = (int8_t)(int)fminf(fmaxf(rintf(v.y / s), clo), chi);
    r[2] = (int8_t)(int)fminf(fmaxf(rintf(v.z / s), clo), chi);
    r[3] = (int8_t)(int)fminf(fmaxf(rintf(v.w / s), clo), chi);
    o4[i] = r;
  }
}

// ------------- i8 GEMM: C[m,n] = (sum_k A[m,k]*W[n,k]) * sA[m] * sW[n] -------------
// int8 codes, exact i32 MFMA accumulation (16x16x64_i8), BK=64, global_load_lds w16.
// mode 0: out[m*N+n]   mode 1: out[((b*Nh+h)*Ss+s)*Dh+d]
__global__ __launch_bounds__(256) void gemm_kernel(
    const int8_t* __restrict__ A, const float* __restrict__ sA,
    const int8_t* __restrict__ W, const float* __restrict__ sW,
    float* __restrict__ out, int M, int N, int K, int mode)
{
  __shared__ __align__(16) int8_t As[128 * 64];
  __shared__ __align__(16) int8_t Bs[128 * 64];
  const int tid = threadIdx.x, lane = tid & 63, wid = tid >> 6;
  const int bm = blockIdx.x * 128, bn = blockIdx.y * 128;
  const int wm = wid >> 1, wn = wid & 1;
  const int l15 = lane & 15, kg = lane >> 4;

  // staging: issue r in {0,1}: LDS byte = r*4096 + wid*1024 + lane*16
  //   -> row = r*64 + wid*16 + (lane>>2), kin = (lane&3)*16
  const int srow = wid * 16 + (lane >> 2);
  const int skin = (lane & 3) * 16;
  const int8_t* gA = A + (size_t)(bm + srow) * K + skin;
  const int8_t* gB = W + (size_t)(bn + srow) * K + skin;
  const size_t half = (size_t)64 * K;
  int8_t* lA = As + wid * 1024;   // wave-uniform base; HW adds lane*16B
  int8_t* lB = Bs + wid * 1024;

  i32x4 acc[4][4] = {};
  for (int k0 = 0; k0 < K; k0 += 64) {
    if (k0) __syncthreads();
    gload_lds16(gA + k0, lA);
    gload_lds16(gA + k0 + half, lA + 4096);
    gload_lds16(gB + k0, lB);
    gload_lds16(gB + k0 + half, lB + 4096);
    __syncthreads();
    i32x4 af[4], bw[4];
#pragma unroll
    for (int f = 0; f < 4; ++f) {
      af[f] = *(const i32x4*)&As[(wm * 64 + f * 16 + l15) * 64 + kg * 16];
      bw[f] = *(const i32x4*)&Bs[(wn * 64 + f * 16 + l15) * 64 + kg * 16];
    }
#pragma unroll
    for (int fm = 0; fm < 4; ++fm)
#pragma unroll
      for (int fn = 0; fn < 4; ++fn)
        acc[fm][fn] = __builtin_amdgcn_mfma_i32_16x16x64_i8(af[fm], bw[fn], acc[fm][fn], 0, 0, 0);
  }
#pragma unroll
  for (int fm = 0; fm < 4; ++fm) {
    const int row0 = bm + wm * 64 + fm * 16 + kg * 4;
#pragma unroll
    for (int fn = 0; fn < 4; ++fn) {
      const int col = bn + wn * 64 + fn * 16 + l15;
      const float swv = sW[col];
#pragma unroll
      for (int j = 0; j < 4; ++j) {
        const int row = row0 + j;
        const float val = (float)acc[fm][fn][j] * sA[row] * swv;
        size_t off;
        if (mode == 0) off = (size_t)row * N + col;
        else {
          int b = row >> 10, si = row & 1023, h = col >> 7, d = col & 127;
          off = (((size_t)(b * Nh + h)) * Ss + si) * Dh + d;
        }
        out[off] = val;
      }
    }
  }
}

// ------------- RoPE + per-row(D=128) quant for Q/K; F = ||x|| / (sqrt(sum qi^2) * 128^0.25) -------------
__global__ __launch_bounds__(256) void rope_quant_kernel(
    const float* __restrict__ xin,                 // [Bh*Ss][128]
    const float* __restrict__ ctab, const float* __restrict__ stab,
    int8_t* __restrict__ xq, float* __restrict__ F)
{
  const int gid = blockIdx.x * 4 + (threadIdx.x >> 6);
  const int lane = threadIdx.x & 63;
  const int srow = gid & (Ss - 1);
  const float* x = xin + (size_t)gid * Dh;
  const float xl = x[lane], xh = x[lane + 64];
  const float c = ctab[srow * 64 + lane], sn = stab[srow * 64 + lane];
  // match numpy's unfused mul/add rounding (no fma contraction)
  const float rl = __fsub_rn(__fmul_rn(xl, c), __fmul_rn(xh, sn));
  const float rh = __fadd_rn(__fmul_rn(xh, c), __fmul_rn(xl, sn));
  float ma = fmaxf(fabsf(rl), fabsf(rh));
  float n2 = rl * rl + rh * rh;
#pragma unroll
  for (int off = 32; off > 0; off >>= 1) {
    ma = fmaxf(ma, __shfl_xor(ma, off));
    n2 += __shfl_xor(n2, off);
  }
  const float s = fmaxf(ma / 127.0f, 1e-8f);
  const float ql = fminf(fmaxf(rintf(rl / s), -128.f), 127.f);
  const float qh = fminf(fmaxf(rintf(rh / s), -128.f), 127.f);
  float nq2 = ql * ql + qh * qh;
#pragma unroll
  for (int off = 32; off > 0; off >>= 1) nq2 += __shfl_xor(nq2, off);
  int8_t* o = xq + (size_t)gid * Dh;
  o[lane] = (int8_t)(int)ql;
  o[lane + 64] = (int8_t)(int)qh;
  if (lane == 0) F[gid] = sqrtf(n2 / nq2) * 0.2973017787506803f;  // 1/128^0.25
}

// ------------- V quant: dequant bf16 stored transposed [Bh][128][Ss] via LDS; a2v factor -------------
__global__ __launch_bounds__(256) void vquant_kernel(
    const float* __restrict__ vin, bf16_t* __restrict__ vdqt, float* __restrict__ a2v)
{
  __shared__ bf16_t s_v[128 * 66];
  const int tid = threadIdx.x, lane = tid & 63;
  const int l15 = lane & 15;
  const int qw = (tid >> 6) * 4 + (lane >> 4);   // quarter-wave id 0..15
  const int bh = blockIdx.x >> 4;
  const int t0 = (blockIdx.x & 15) * 64;
  for (int it = 0; it < 4; ++it) {
    const int tt = qw * 4 + it;                   // 0..63
    const size_t gid = (size_t)bh * Ss + t0 + tt;
    const float4 va = *(const float4*)(vin + gid * Dh + l15 * 8);
    const float4 vb = *(const float4*)(vin + gid * Dh + l15 * 8 + 4);
    float m = fmaxf(fmaxf(fmaxf(fabsf(va.x), fabsf(va.y)), fmaxf(fabsf(va.z), fabsf(va.w))),
                    fmaxf(fmaxf(fabsf(vb.x), fabsf(vb.y)), fmaxf(fabsf(vb.z), fabsf(vb.w))));
    float n2 = va.x * va.x + va.y * va.y + va.z * va.z + va.w * va.w +
               vb.x * vb.x + vb.y * vb.y + vb.z * vb.z + vb.w * vb.w;
#pragma unroll
    for (int off = 1; off < 16; off <<= 1) {
      m = fmaxf(m, __shfl_xor(m, off));
      n2 += __shfl_xor(n2, off);
    }
    const float s = fmaxf(m / 127.0f, 1e-8f);
    float q[8] = {va.x, va.y, va.z, va.w, vb.x, vb.y, vb.z, vb.w};
    float nq2 = 0.f;
#pragma unroll
    for (int e = 0; e < 8; ++e) {
      q[e] = fminf(fmaxf(rintf(q[e] / s), -128.f), 127.f);
      nq2 += q[e] * q[e];
      s_v[(l15 * 8 + e) * 66 + tt] = (bf16_t)(q[e] * s);
    }
#pragma unroll
    for (int off = 1; off < 16; off <<= 1) nq2 += __shfl_xor(nq2, off);
    if (l15 == 0) a2v[gid] = s * sqrtf(nq2) / sqrtf(n2);
  }
  __syncthreads();
  // coalesced write-out: thread -> (row, half): 32 bf16 = 64 B
  const int r = tid >> 1, hc = (tid & 1) * 32;
  const bf16_t* src = &s_v[r * 66 + hc];
  bf16_t* dst = vdqt + ((size_t)bh * Dh + r) * Ss + t0 + hc;
#pragma unroll
  for (int k = 0; k < 4; ++k) {
    bf16x8 t;
#pragma unroll
    for (int e = 0; e < 8; ++e) t[e] = src[k * 8 + e];
    *(bf16x8*)(dst + k * 8) = t;
  }
}

// ------------- fused attention: i8 QK^T (causal) -> softmax -> P-quant -> bf16 PV -------------
__global__ __launch_bounds__(256) void attn_kernel(
    const int8_t* __restrict__ qq, const int8_t* __restrict__ kq,
    const bf16_t* __restrict__ vdqt,
    const float* __restrict__ Fq, const float* __restrict__ Fk,
    const float* __restrict__ A2v, float* __restrict__ oattn)
{
  const int bh = blockIdx.y, b = bh >> 5, h = bh & 31;
  const int q0 = blockIdx.x * 16;
  const int nfc2 = ((int)blockIdx.x + 2) & ~1;   // 16-col chunks (even count)
  const int tid = threadIdx.x, lane = tid & 63, wid = tid >> 6;
  const int l15 = lane & 15, kg = lane >> 4, kof = kg * 8;
  __shared__ __align__(16) bf16_t s_pq[16][1024];
  __shared__ float s_rmax[4][16];
  __shared__ float s_rsum[4][16];

  // contiguous per-wave chunk range: wave wid handles [c0, c0+cn)
  const int cbase = nfc2 >> 2, crem = nfc2 & 3;
  const int cn = cbase + (wid < crem ? 1 : 0);
  const int c0 = wid * cbase + (wid < crem ? wid : crem);

  const size_t bhS = (size_t)bh * Ss;
  const int8_t* qbase = qq + (bhS + q0) * Dh;
  i32x4 aq0 = *(const i32x4*)(qbase + l15 * Dh + kg * 16);
  i32x4 aq1 = *(const i32x4*)(qbase + l15 * Dh + 64 + kg * 16);
  float fq[4];
#pragma unroll
  for (int j = 0; j < 4; ++j) fq[j] = Fq[bhS + q0 + kg * 4 + j];

  // --- QK^T over this wave's causal chunk range (2 MFMA per chunk, K=64 each) ---
  float sc[16][4];
  float pm[4] = {NEG_INF_F, NEG_INF_F, NEG_INF_F, NEG_INF_F};
#pragma unroll
  for (int i = 0; i < 16; ++i) {
    if (i >= cn) break;
    const int fc = c0 + i;
    const int kc = fc * 16;
    const int8_t* kbase = kq + (bhS + kc) * Dh;
    i32x4 bk0 = *(const i32x4*)(kbase + l15 * Dh + kg * 16);
    i32x4 bk1 = *(const i32x4*)(kbase + l15 * Dh + 64 + kg * 16);
    i32x4 c = {};
    c = __builtin_amdgcn_mfma_i32_16x16x64_i8(aq0, bk0, c, 0, 0, 0);
    c = __builtin_amdgcn_mfma_i32_16x16x64_i8(aq1, bk1, c, 0, 0, 0);
    const int col = kc + l15;
    const float fk = Fk[bhS + col];
#pragma unroll
    for (int j = 0; j < 4; ++j) {
      const float v = (float)c[j] * fq[j] * fk;
      sc[i][j] = (col <= q0 + kg * 4 + j) ? v : NEG_INF_F;   // exact causal mask
      pm[j] = fmaxf(pm[j], sc[i][j]);
    }
  }
  // --- row max: 16-lane group, then cross-wave via LDS ---
#pragma unroll
  for (int j = 0; j < 4; ++j) {
#pragma unroll
    for (int off = 1; off < 16; off <<= 1) pm[j] = fmaxf(pm[j], __shfl_xor(pm[j], off));
  }
  if (l15 == 0) {
#pragma unroll
    for (int j = 0; j < 4; ++j) s_rmax[wid][kg * 4 + j] = pm[j];
  }
  __syncthreads();
  float mrow[4], zp[4] = {0.f, 0.f, 0.f, 0.f};
#pragma unroll
  for (int j = 0; j < 4; ++j) {
    const int r = kg * 4 + j;
    mrow[j] = fmaxf(fmaxf(s_rmax[0][r], s_rmax[1][r]), fmaxf(s_rmax[2][r], s_rmax[3][r]));
  }
  // --- exp, Z partial, P-quant into XOR-swizzled LDS (pq = round(127*e), exact) ---
#pragma unroll
  for (int i = 0; i < 16; ++i) {
    if (i >= cn) break;
    const int col = (c0 + i) * 16 + l15;
#pragma unroll
    for (int j = 0; j < 4; ++j) {
      const float e = __expf(sc[i][j] - mrow[j]);
      zp[j] += e;
      const int r = kg * 4 + j;
      s_pq[r][col ^ ((r & 7) << 3)] = (bf16_t)fminf(rintf(127.0f * e), 127.0f);
    }
  }
#pragma unroll
  for (int j = 0; j < 4; ++j) {
#pragma unroll
    for (int off = 1; off < 16; off <<= 1) zp[j] += __shfl_xor(zp[j], off);
  }
  if (l15 == 0) {
#pragma unroll
    for (int j = 0; j < 4; ++j) s_rsum[wid][kg * 4 + j] = zp[j];
  }
  __syncthreads();
  float osc[4];
#pragma unroll
  for (int j = 0; j < 4; ++j) {
    const int r = kg * 4 + j;
    const float Z = ((s_rsum[0][r] + s_rsum[1][r]) + (s_rsum[2][r] + s_rsum[3][r]));
    const float pmax = 1.0f / Z;                  // softmax row max
    const float sp = fmaxf(pmax / 127.0f, 1e-8f); // p scale
    osc[j] = sp / A2v[bhS + q0 + r];
  }
  // --- PV over causal range: this wave owns 32 of 128 d-columns ---
  const int nkk = nfc2 >> 1;
  f32x4 oacc[2] = {};
  const int d0 = wid * 32;
  const bf16_t* vb0 = vdqt + ((size_t)bh * Dh + d0 + l15) * Ss;
  const bf16_t* vb1 = vb0 + (size_t)16 * Ss;
  for (int kk = 0; kk < nkk; ++kk) {
    const int kidx = kk * 32 + kof;
    bf16x8 ap = *(const bf16x8*)&s_pq[l15][kidx ^ ((l15 & 7) << 3)];
    bf16x8 b0 = *(const bf16x8*)(vb0 + kidx);
    bf16x8 b1 = *(const bf16x8*)(vb1 + kidx);
    oacc[0] = __builtin_amdgcn_mfma_f32_16x16x32_bf16(ap, b0, oacc[0], 0, 0, 0);
    oacc[1] = __builtin_amdgcn_mfma_f32_16x16x32_bf16(ap, b1, oacc[1], 0, 0, 0);
  }
#pragma unroll
  for (int f = 0; f < 2; ++f) {
    const int col = d0 + f * 16 + l15;
#pragma unroll
    for (int j = 0; j < 4; ++j) {
      const int r = kg * 4 + j;
      oattn[((size_t)b * Ss + q0 + r) * Hid + h * Dh + col] = oacc[f][j] * osc[j];
    }
  }
}

extern "C" void kernel_launch(void* const* d_in, const int* in_sizes, int n_in,
                              void* d_out, int out_size, void* d_ws, size_t ws_size,
                              hipStream_t stream)
{
  const float* hidden = (const float*)d_in[0];
  const float* wq = (const float*)d_in[1];
  const float* wk = (const float*)d_in[2];
  const float* wv = (const float*)d_in[3];
  const float* wo = (const float*)d_in[4];
  float* out = (float*)d_out;

  // ---- workspace layout with aggressive reuse (~90 MiB total) ----
  char* p = (char*)d_ws;
  auto alloc = [&](size_t bytes) -> char* {
    char* r = p; p += (bytes + 255) & ~(size_t)255; return r;
  };
  int8_t* xq   = (int8_t*)alloc((size_t)Mr * Hid);                     // act codes; later reused for oq
  int8_t* wbuf = (int8_t*)alloc((size_t)Hid * Hid);                    // shared weight codes
  float*  projf= (float*) alloc((size_t)Bh * Ss * Dh * sizeof(float)); // shared proj out; later oat
  int8_t* qqb  = (int8_t*)alloc((size_t)Bh * Ss * Dh);
  int8_t* kqb  = (int8_t*)alloc((size_t)Bh * Ss * Dh);
  bf16_t* vdqt = (bf16_t*)alloc((size_t)Bh * Dh * Ss * sizeof(bf16_t));
  float* sxa = (float*)alloc((size_t)Mr * sizeof(float));
  float* sw  = (float*)alloc((size_t)Hid * sizeof(float));
  float* Fq  = (float*)alloc((size_t)Bh * Ss * sizeof(float));
  float* Fk  = (float*)alloc((size_t)Bh * Ss * sizeof(float));
  float* A2v = (float*)alloc((size_t)Bh * Ss * sizeof(float));
  float* soa = (float*)alloc((size_t)Mr * sizeof(float));
  float* ctab = (float*)alloc((size_t)Ss * 64 * sizeof(float));
  float* stab = (float*)alloc((size_t)Ss * 64 * sizeof(float));
  float*  oat = projf;           // projf dead after vquant
  int8_t* oq  = xq;              // xq dead after the three projections

  rope_table_kernel<<<Ss * 64 / 256, 256, 0, stream>>>(ctab, stab);
  quant_rows_kernel<<<Mr, 256, 0, stream>>>(hidden, xq, sxa, Hid, 127.f, -128.f, 127.f);

  dim3 gg(Mr / 128, Hid / 128);
  // Q
  quant_rows_kernel<<<Hid, 256, 0, stream>>>(wq, wbuf, sw, Hid, 7.f, -8.f, 7.f);
  gemm_kernel<<<gg, 256, 0, stream>>>(xq, sxa, wbuf, sw, projf, Mr, Hid, Hid, 1);
  rope_quant_kernel<<<Bh * Ss / 4, 256, 0, stream>>>(projf, ctab, stab, qqb, Fq);
  // K
  quant_rows_kernel<<<Hid, 256, 0, stream>>>(wk, wbuf, sw, Hid, 7.f, -8.f, 7.f);
  gemm_kernel<<<gg, 256, 0, stream>>>(xq, sxa, wbuf, sw, projf, Mr, Hid, Hid, 1);
  rope_quant_kernel<<<Bh * Ss / 4, 256, 0, stream>>>(projf, ctab, stab, kqb, Fk);
  // V
  quant_rows_kernel<<<Hid, 256, 0, stream>>>(wv, wbuf, sw, Hid, 7.f, -8.f, 7.f);
  gemm_kernel<<<gg, 256, 0, stream>>>(xq, sxa, wbuf, sw, projf, Mr, Hid, Hid, 1);
  vquant_kernel<<<Bh * 16, 256, 0, stream>>>(projf, vdqt, A2v);

  dim3 ga(Ss / 16, Bh);
  attn_kernel<<<ga, 256, 0, stream>>>(qqb, kqb, vdqt, Fq, Fk, A2v, oat);

  quant_rows_kernel<<<Mr, 256, 0, stream>>>(oat, oq, soa, Hid, 127.f, -128.f, 127.f);
  quant_rows_kernel<<<Hid, 256, 0, stream>>>(wo, wbuf, sw, Hid, 7.f, -8.f, 7.f);
  gemm_kernel<<<gg, 256, 0, stream>>>(oq, soa, wbuf, sw, out, Mr, Hid, Hid, 0);
}